// Round 13
// baseline (214.802 us; speedup 1.0000x reference)
//
#include <hip/hip_runtime.h>
#include <hip/hip_bf16.h>
#include <stdint.h>

#define BB 32
#define GG 100
#define AA 8400
#define TPB 256
#define NCH 33                         // ceil(8400/256) chunks per image
#define TKB 512                        // kB block size (8 waves)
#define NPERS 1024                     // kB persistent blocks (4/CU x 256 CU)
#define BA (BB*AA)
#define NG (BB*GG)
#define NB2 (BB*GG)                    // kR blocks / partial count
#define NITB 17                        // ceil(AA/TKB) kB screen iterations
#define PCAP 8416                      // positives cap (>= AA, cannot overflow)
#define GCAP 128                       // geo cap (provably <= 75 per gt)
#define SCAP (GG*10)                   // selection slots per image (g*10+k)

typedef __hip_bfloat16 bf16;

struct P {
  const void *outs, *labs, *ss;
  float4 *box4, *gtb, *gtc;           // per-anchor box; per-gt box/center
  float2 *aux2;                       // per-anchor (fg? area : -area, cpk bits)
  float *pcc, *zl;                    // per-anchor cls-cost / cls logit
  int   *sel_a;                       // [BB][SCAP] selected anchor id, -1 empty
  float *sel_iou;                     // [BB][SCAP] its iou
  int   *cnt, *own;                   // per-anchor selection count / min slot
  float *pb, *pf;                     // per-(b,g) BCE / fg partials
  int *gmax, *qh;
  float *out;
};

// runtime input-dtype detection: strides[0]==8.0
// f32 word 0x41000000 ; bf16 pair (8.0,8.0) 0x41004100
__device__ __forceinline__ int dtypeFlag(const void* ss){
  return (((const uint32_t*)ss)[0] == 0x41000000u) ? 1 : 0;
}
__device__ __forceinline__ float ld(const void* p, int i, int isf32){
  return isf32 ? ((const float*)p)[i] : __bfloat162float(((const bf16*)p)[i]);
}
// analytic anchor geometry (exact: ints + pow2 strides exact in f32/bf16)
__device__ __forceinline__ void ageom(int a, float& xc, float& yc, float& r){
  int x, y, s;
  if (a < 6400){ x = a % 80; y = a / 80; s = 8; }
  else if (a < 8000){ int q = a - 6400; x = q % 40; y = q / 40; s = 16; }
  else { int q = a - 8000; x = q % 20; y = q / 20; s = 32; }
  float fs = (float)s;
  xc = ((float)x + 0.5f) * fs;
  yc = ((float)y + 0.5f) * fs;
  r  = 2.5f * fs;
}
// pack integer center + level: xc(10) | yc(10)<<10 | lvl<<20
__device__ __forceinline__ uint32_t apack2(int a){
  int x, y, s, lvl;
  if (a < 6400){ x = a % 80; y = a / 80; s = 8; lvl = 0; }
  else if (a < 8000){ int q = a - 6400; x = q % 40; y = q / 40; s = 16; lvl = 1; }
  else { int q = a - 8000; x = q % 20; y = q / 20; s = 32; lvl = 2; }
  return (uint32_t)(x*s + s/2) | ((uint32_t)(y*s + s/2) << 10) | ((uint32_t)lvl << 20);
}

// ---- kA: gt structs + per-anchor staging + fg (identity layout) -----------
// v14: unchanged from r13 except qh=0 init (work queue for persistent kB).
__global__ __launch_bounds__(TPB) void kA(P p){
  __shared__ float4 s_gtb[GG], s_gtc[GG];
  __shared__ float s_o[TPB*6];
  __shared__ int s_ng;
  int t = threadIdx.x;
  int c = blockIdx.x, b = blockIdx.y;
  int isf = dtypeFlag(p.ss);
  if (t == 0) s_ng = 0;
  if (c == 0 && b == 0 && t == 0) *p.qh = 0;       // kB work-queue head
  {
    int s = c*TPB + t;
    if (s < SCAP) p.sel_a[b*SCAP + s] = -1;        // empty slot marker
  }
  int nel = min(TPB*6, AA*6 - c*(TPB*6));      // floats in this chunk
  if (isf){
    const float4* src = (const float4*)((const float*)p.outs + (size_t)b*AA*6 + (size_t)c*(TPB*6));
    float4* dst = (float4*)s_o;
    for (int i = t; i < nel/4; i += TPB) dst[i] = src[i];
  } else {
    const uint4* src = (const uint4*)((const bf16*)p.outs + (size_t)b*AA*6 + (size_t)c*(TPB*6));
    for (int i = t; i < nel/8; i += TPB){
      uint4 u = src[i];
      int o = i*8;
      s_o[o+0]=__uint_as_float(u.x<<16); s_o[o+1]=__uint_as_float(u.x&0xffff0000u);
      s_o[o+2]=__uint_as_float(u.y<<16); s_o[o+3]=__uint_as_float(u.y&0xffff0000u);
      s_o[o+4]=__uint_as_float(u.z<<16); s_o[o+5]=__uint_as_float(u.z&0xffff0000u);
      s_o[o+6]=__uint_as_float(u.w<<16); s_o[o+7]=__uint_as_float(u.w&0xffff0000u);
    }
  }
  __syncthreads();
  if (t < GG){
    int i = b*GG + t;
    float l0 = ld(p.labs, i*5  , isf);
    float gcx= ld(p.labs, i*5+1, isf);
    float gcy= ld(p.labs, i*5+2, isf);
    float gw = ld(p.labs, i*5+3, isf);
    float gh = ld(p.labs, i*5+4, isf);
    int valid = (l0+gcx+gcy+gw+gh) > 0.f;
    float4 vb = make_float4(gcx-gw*0.5f, gcy-gh*0.5f, gcx+gw*0.5f, gcy+gh*0.5f);
    float4 vc = make_float4(gcx, gcy, gw*gh, valid ? 1.f : 0.f);
    s_gtb[t] = vb; s_gtc[t] = vc;
    if (c == 0){ p.gtb[i] = vb; p.gtc[i] = vc; }
    if (valid) atomicMax(&s_ng, t+1);
  }
  __syncthreads();
  int ng = s_ng;
  if (c == 0 && t == 0) p.gmax[b] = ng;
  int a = c*TPB + t;
  if (a < AA){
    float cx=s_o[t*6], cy=s_o[t*6+1], w=s_o[t*6+2], h=s_o[t*6+3], ob=s_o[t*6+4], cl=s_o[t*6+5];
    int idx = b*AA + a;
    p.box4[idx] = make_float4(cx-w*0.5f, cy-h*0.5f, cx+w*0.5f, cy+h*0.5f);
    float so = 1.f/(1.f+expf(-ob));
    float sc = 1.f/(1.f+expf(-cl));
    float pccv = -logf(sqrtf(sc*so) + 1e-9f);
    float xc, yc, r; ageom(a, xc, yc, r);
    int fg = 0;
    for (int g = 0; g < ng; ++g){
      float4 gb = s_gtb[g], gc = s_gtc[g];
      bool inb = (xc>gb.x)&&(xc<gb.z)&&(yc>gb.y)&&(yc<gb.w);
      bool inc = (fabsf(xc-gc.x)<r)&&(fabsf(yc-gc.y)<r);
      fg |= (gc.w != 0.f) && (inb||inc);
    }
    float area = w*h;                       // >= 16 (w,h >= 4): sign trick safe
    p.aux2[idx] = make_float2(fg ? area : -area, __uint_as_float(apack2(a)));
    p.pcc[idx] = pccv;
    p.zl [idx] = cl;
    p.cnt[idx] = 0;
    p.own[idx] = 0x7fffffff;
  }
}

// ---- kB: persistent work-queue dyn_k + selection --------------------------
// v14: PERSISTENT BLOCKS + ATOMIC WORK QUEUE. r12 counters: LDS 34.8KB +
// 512thr => 4 blocks/CU = 32 waves = nominal 100% occupancy, measured 40%
// -- residency loss is pure block-count imbalance (1600 real items ~6.25/CU,
// integer skew + drain tail). 1024 blocks (exact 4/CU) pop items from qh:
// no CU idles while items remain; invalid items cost one pop. Item body is
// r12 verbatim (absmax 0); items independent, writes = own slots +
// commutative atomics -> order-invariant, bit-exact.
__global__ __launch_bounds__(TKB) void kB(P p){
  __shared__ float s_pos[PCAP];
  __shared__ float s_gcost[GCAP];
  __shared__ int   s_gpos[GCAP];
  __shared__ int   s_pcnt, s_gcnt, s_item;
  int t = threadIdx.x;
  int lane = t & 63, wid = t >> 6;
  unsigned long long lmlt = (1ull<<lane) - 1ull;
  for (;;){
    __syncthreads();                        // prev selection done; s_* reusable
    if (t == 0){
      s_item = atomicAdd(p.qh, 1);
      s_pcnt = 0; s_gcnt = 0;
    }
    __syncthreads();
    int item = s_item;
    if (item >= BB*GG) break;               // uniform: queue drained
    int b = item / GG, g = item - b*GG;
    float4 gc = p.gtc[b*GG+g];
    if (gc.w == 0.f) continue;              // uniform skip (all threads)
    float4 gb = p.gtb[b*GG+g];
    float glx=gb.x, gly=gb.y, ghx=gb.z, ghy=gb.w, gcx=gc.x, gcy=gc.y, ga=gc.z;
    int base = b*AA;

    // main screen over all AA anchors; heavy math only on hits
    for (int it = 0; it < NITB; ++it){
      int pos = it*TKB + t;
      bool ovl = false, geo = false;
      float v = 0.f, cst = 0.f;
      if (pos < AA){
        float2 aux = p.aux2[base+pos];
        float4 bx  = p.box4[base+pos];
        bool fg = aux.x > 0.f;
        uint32_t u = __float_as_uint(aux.y);
        float xc = (float)(u & 1023u), yc = (float)((u>>10)&1023u);
        float r  = (float)(20u << (u>>20));
        bool inb = (xc>glx)&&(xc<ghx)&&(yc>gly)&&(yc<ghy);
        geo = inb && (fabsf(xc-gcx)<r) && (fabsf(yc-gcy)<r);   // geo => fg
        float tlx=fmaxf(glx,bx.x), tly=fmaxf(gly,bx.y);
        float brx=fminf(ghx,bx.z), bry=fminf(ghy,bx.w);
        float iw=brx-tlx, ih=bry-tly;
        ovl = fg && (iw>0.f) && (ih>0.f);
        if (ovl | geo){
          float area = fabsf(aux.x);
          float inter = fmaxf(iw,0.f)*fmaxf(ih,0.f);
          v = inter/(ga + area - inter + 1e-12f);
          if (geo) cst = p.pcc[base+pos] + 3.f*(-logf(v+1e-8f));
        }
      }
      unsigned long long m1 = __ballot(ovl);
      if (m1){
        int ldr = (int)(__ffsll(m1)-1);
        int off;
        if (lane == ldr) off = atomicAdd(&s_pcnt, __popcll(m1));
        off = __shfl(off, ldr);
        if (ovl) s_pos[off + __popcll(m1 & lmlt)] = v;
      }
      unsigned long long m2 = __ballot(geo);
      if (m2){
        int ldr = (int)(__ffsll(m2)-1);
        int off;
        if (lane == ldr) off = atomicAdd(&s_gcnt, __popcll(m2));
        off = __shfl(off, ldr);
        if (geo){
          int q = off + __popcll(m2 & lmlt);
          s_gcost[q] = cst; s_gpos[q] = pos;
        }
      }
    }
    __syncthreads();
    if (wid == 0){                          // wave 0 selects; others loop back
      int pcnt = s_pcnt, gcnt = s_gcnt;     // gcnt <= 75 < GCAP

      // dk: top-10 positives by pop-extraction over s_pos (values only;
      // descending add order == jnp top_k sum order; zeros add exactly 0)
      float lmax = -1.f;
      for (int i = lane; i < pcnt; i += 64) lmax = fmaxf(lmax, s_pos[i]);
      float sum = 0.f;
      for (int k = 0; k < 10; ++k){
        float gv = lmax;
#pragma unroll
        for (int off=32; off; off>>=1) gv = fmaxf(gv, __shfl_xor(gv, off));
        if (gv <= 0.f) break;
        sum += gv;
        unsigned long long ms = __ballot(lmax == gv);
        if ((int)(__ffsll(ms)-1) == lane){  // unique owner: remove 1 instance
          bool fnd = false; float nl = -1.f;
          for (int i = lane; i < pcnt; i += 64){
            float vv = s_pos[i];
            if (!fnd && vv == gv){ fnd = true; vv = -1.f; s_pos[i] = vv; }
            nl = fmaxf(nl, vv);
          }
          lmax = nl;
        }
      }
      int dk = (int)sum; if (dk<1) dk=1; if (dk>10) dk=10;

      // selection among geo (<=2 entries/lane; all geo < all non-geo cost)
      float c0=3.0e38f, c1=3.0e38f; int p0=0x7fffffff, p1=0x7fffffff;
      if (lane < gcnt){ c0 = s_gcost[lane]; p0 = s_gpos[lane]; }
      if (lane+64 < gcnt){ c1 = s_gcost[lane+64]; p1 = s_gpos[lane+64]; }
      if (c1 < c0 || (c1==c0 && p1<p0)){
        float tc=c0; c0=c1; c1=tc; int tp=p0; p0=p1; p1=tp;
      }
      int mysel = -1, take = 0;
      for (int k = 0; k < dk; ++k){
        float gv=c0; int gi=p0;
#pragma unroll
        for (int off=32; off; off>>=1){
          float ov=__shfl_xor(gv,off); int oi=__shfl_xor(gi,off);
          if (ov<gv || (ov==gv && oi<gi)){ gv=ov; gi=oi; }
        }
        if (gv >= 2.9e38f) break;           // geo exhausted
        if (lane == k) mysel = gi;
        take++;
        if (c0==gv && p0==gi){ c0=c1; p0=p1; c1=3.0e38f; p1=0x7fffffff; }
      }

      // rare fallback: need (dk-take) non-geo picks; exact k-th smallest via
      // repeated rescan excluding previous picks by strict lex >
      float lastc = -3.0e38f; int lastp = -1;
      for (int k = take; k < dk; ++k){
        float bc = 3.0e38f; int bp = 0x7fffffff;
        int n64 = (AA + 63) >> 6;
        for (int it = 0; it < n64; ++it){
          int pos = (it<<6) + lane;
          if (pos < AA){
            float2 aux = p.aux2[base+pos];
            bool fg = aux.x > 0.f;
            if (fg){
              uint32_t u = __float_as_uint(aux.y);
              float xc = (float)(u & 1023u), yc = (float)((u>>10)&1023u);
              float r  = (float)(20u << (u>>20));
              bool inb = (xc>glx)&&(xc<ghx)&&(yc>gly)&&(yc<ghy);
              bool geo2 = inb && (fabsf(xc-gcx)<r) && (fabsf(yc-gcy)<r);
              if (!geo2){
                float4 bx = p.box4[base+pos];
                float tlx=fmaxf(glx,bx.x), tly=fmaxf(gly,bx.y);
                float brx=fminf(ghx,bx.z), bry=fminf(ghy,bx.w);
                float iw=fmaxf(brx-tlx,0.f), ih=fmaxf(bry-tly,0.f);
                float inter=iw*ih;
                float area = fabsf(aux.x);
                float v = inter/(ga + area - inter + 1e-12f);
                float cst = p.pcc[base+pos] + 3.f*(-logf(v+1e-8f)) + 100000.f;
                bool gt = (cst > lastc) || (cst == lastc && pos > lastp);
                bool lt = (cst < bc)   || (cst == bc   && pos < bp);
                if (gt && lt){ bc = cst; bp = pos; }
              }
            }
          }
        }
#pragma unroll
        for (int off=32; off; off>>=1){
          float ov=__shfl_xor(bc,off); int oi=__shfl_xor(bp,off);
          if (ov<bc || (ov==bc && oi<bp)){ bc=ov; bp=oi; }
        }
        if (bc >= 2.9e38f) break;           // candidates exhausted
        if (lane == k) mysel = bp;
        lastc = bc; lastp = bp;
      }

      if (mysel >= 0){                      // lanes 0..dk-1 hold selections
        int a = mysel;                      // pos == anchor id
        float4 bx = p.box4[base+a];
        float area = fabsf(p.aux2[base+a].x);
        float tlx=fmaxf(glx,bx.x), tly=fmaxf(gly,bx.y);
        float brx=fminf(ghx,bx.z), bry=fminf(ghy,bx.w);
        float iw=fmaxf(brx-tlx,0.f), ih=fmaxf(bry-tly,0.f);
        float inter=iw*ih;
        float iou=inter/(ga + area - inter + 1e-12f);
        int slot = g*10 + lane;             // deterministic slot id
        p.sel_a [b*SCAP + slot] = a;
        p.sel_iou[b*SCAP + slot] = iou;
        atomicAdd(&p.cnt[base+a], 1);
        atomicMin(&p.own[base+a], slot);    // commutative -> deterministic owner
      }
    }
  }
}

// ---- kR: per-(b,g) resolution + BCE partials (grid 3200, 1 wave) ----------
__global__ __launch_bounds__(64) void kR(P p){
  int lane = threadIdx.x;
  int item = blockIdx.x;
  int b = item / GG, g = item - b*GG;
  int base = b*AA;
  float bce = 0.f, fgv = 0.f;
  if (lane < 10){
    int slot = g*10 + lane;
    int a = p.sel_a[b*SCAP + slot];
    if (a >= 0 && p.own[base+a] == slot){   // this slot owns the anchor
      int cgt = p.cnt[base+a];
      float iouv;
      if (cgt == 1){
        iouv = p.sel_iou[b*SCAP + slot];
      } else {
        // verbatim conflicted-anchor recompute (first-index argmin)
        float area = fabsf(p.aux2[base+a].x);
        float pccv = p.pcc[base+a];
        float4 bx = p.box4[base+a];
        float xc,yc,r; ageom(a,xc,yc,r);
        int ng = p.gmax[b];
        float best=3.9e38f, biou=0.f;
        for (int g2=0; g2<ng; ++g2){
          float4 gbb = p.gtb[b*GG+g2], gcc = p.gtc[b*GG+g2];
          float cost, iou2 = 0.f;
          if (gcc.w != 0.f){
            float tlx=fmaxf(gbb.x,bx.x), tly=fmaxf(gbb.y,bx.y);
            float brx=fminf(gbb.z,bx.z), bry=fminf(gbb.w,bx.w);
            float iw=fmaxf(brx-tlx,0.f), ih=fmaxf(bry-tly,0.f);
            float inter=iw*ih;
            iou2 = inter/(gcc.z + area - inter + 1e-12f);
            bool inb=(xc>gbb.x)&&(xc<gbb.z)&&(yc>gbb.y)&&(yc<gbb.w);
            bool inc=(fabsf(xc-gcc.x)<r)&&(fabsf(yc-gcc.y)<r);
            cost = pccv + 3.f*(-logf(iou2+1e-8f)) + ((inb&&inc)?0.f:100000.f);
          } else cost = 1e9f;
          if (cost < best){ best=cost; biou=iou2; }
        }
        iouv = biou;
      }
      float z = p.zl[base+a];
      float e = expf(-fabsf(z));
      float spz = fmaxf(z,0.f)+log1pf(e);
      float spn = fmaxf(-z,0.f)+log1pf(e);
      bce = iouv*spn + (1.f-iouv)*spz;
      fgv = 1.f;
    }
  }
#pragma unroll
  for (int off=32; off; off>>=1){
    bce += __shfl_xor(bce, off);
    fgv += __shfl_xor(fgv, off);
  }
  if (lane == 0){ p.pb[item] = bce; p.pf[item] = fgv; }
}

// ---- kD: reduce 3200 partials + finalize (1 block) -------------------------
__global__ __launch_bounds__(TPB) void kD(P p){
  int t = threadIdx.x;
  float sb=0.f, sf=0.f;
  for (int i = t; i < NB2; i += TPB){ sb += p.pb[i]; sf += p.pf[i]; }
#pragma unroll
  for (int off=32; off; off>>=1){
    sb += __shfl_xor(sb, off);
    sf += __shfl_xor(sf, off);
  }
  __shared__ float s_b[4], s_f[4];
  int lane = t & 63, wid = t >> 6;
  if (lane==0){ s_b[wid]=sb; s_f[wid]=sf; }
  __syncthreads();
  if (t==0){
    float tb=s_b[0]+s_b[1]+s_b[2]+s_b[3];
    float tf=s_f[0]+s_f[1]+s_f[2]+s_f[3];
    p.out[0] = tb / fmaxf(tf, 1.f);
  }
}

extern "C" void kernel_launch(void* const* d_in, const int* in_sizes, int n_in,
                              void* d_out, int out_size, void* d_ws, size_t ws_size,
                              hipStream_t stream) {
  P p;
  p.outs = d_in[0];
  p.labs = d_in[1];
  p.ss   = d_in[4];
  char* w = (char*)d_ws;
  p.box4  = (float4*)w; w += (size_t)BA*sizeof(float4);
  p.gtb   = (float4*)w; w += (size_t)NG*sizeof(float4);
  p.gtc   = (float4*)w; w += (size_t)NG*sizeof(float4);
  p.aux2  = (float2*)w; w += (size_t)BA*sizeof(float2);
  p.pcc   = (float*)w;  w += (size_t)BA*sizeof(float);
  p.zl    = (float*)w;  w += (size_t)BA*sizeof(float);
  p.sel_a = (int*)w;    w += (size_t)BB*SCAP*sizeof(int);
  p.sel_iou=(float*)w;  w += (size_t)BB*SCAP*sizeof(float);
  p.cnt   = (int*)w;    w += (size_t)BA*sizeof(int);
  p.own   = (int*)w;    w += (size_t)BA*sizeof(int);
  p.gmax  = (int*)w;    w += (size_t)BB*sizeof(int);
  p.qh    = (int*)w;    w += sizeof(int);
  p.pb    = (float*)w;  w += (size_t)NB2*sizeof(float);
  p.pf    = (float*)w;  w += (size_t)NB2*sizeof(float);
  p.out   = (float*)d_out;

  kA<<<dim3(NCH, BB), TPB, 0, stream>>>(p);
  kB<<<NPERS, TKB, 0, stream>>>(p);
  kR<<<NB2, 64, 0, stream>>>(p);
  kD<<<1, TPB, 0, stream>>>(p);
}

// Round 14
// 151.597 us; speedup vs baseline: 1.4169x; 1.4169x over previous
//
#include <hip/hip_runtime.h>
#include <hip/hip_bf16.h>
#include <stdint.h>

#define BB 32
#define GG 100
#define AA 8400
#define TPB 256
#define NCH 33                         // ceil(8400/256) chunks per image
#define TKB 512                        // kB block size (8 waves)
#define BA (BB*AA)
#define NG (BB*GG)
#define NB2 (BB*GG)                    // kR blocks / partial count
#define NITB 17                        // ceil(AA/TKB) kB screen iterations
#define PCAP 8416                      // positives cap (>= AA, cannot overflow)
#define GCAP 128                       // geo cap (provably <= 75 per gt)
#define SCAP (GG*10)                   // selection slots per image (g*10+k)

typedef __hip_bfloat16 bf16;

struct P {
  const void *outs, *labs, *ss;
  float4 *box4, *gtb, *gtc;           // per-anchor box; per-gt box/center
  float2 *aux2;                       // per-anchor (fg? area : -area, cpk bits)
  float *pcc, *zl;                    // per-anchor cls-cost / cls logit
  int   *sel_a;                       // [BB][SCAP] selected anchor id, -1 empty
  float *sel_iou;                     // [BB][SCAP] its iou
  int   *cnt, *own;                   // per-anchor selection count / min slot
  float *pb, *pf;                     // per-(b,g) BCE / fg partials
  int *gmax;
  float *out;
};

// runtime input-dtype detection: strides[0]==8.0
// f32 word 0x41000000 ; bf16 pair (8.0,8.0) 0x41004100
__device__ __forceinline__ int dtypeFlag(const void* ss){
  return (((const uint32_t*)ss)[0] == 0x41000000u) ? 1 : 0;
}
__device__ __forceinline__ float ld(const void* p, int i, int isf32){
  return isf32 ? ((const float*)p)[i] : __bfloat162float(((const bf16*)p)[i]);
}
// analytic anchor geometry (exact: ints + pow2 strides exact in f32/bf16)
__device__ __forceinline__ void ageom(int a, float& xc, float& yc, float& r){
  int x, y, s;
  if (a < 6400){ x = a % 80; y = a / 80; s = 8; }
  else if (a < 8000){ int q = a - 6400; x = q % 40; y = q / 40; s = 16; }
  else { int q = a - 8000; x = q % 20; y = q / 20; s = 32; }
  float fs = (float)s;
  xc = ((float)x + 0.5f) * fs;
  yc = ((float)y + 0.5f) * fs;
  r  = 2.5f * fs;
}
// pack integer center + level: xc(10) | yc(10)<<10 | lvl<<20
__device__ __forceinline__ uint32_t apack2(int a){
  int x, y, s, lvl;
  if (a < 6400){ x = a % 80; y = a / 80; s = 8; lvl = 0; }
  else if (a < 8000){ int q = a - 6400; x = q % 40; y = q / 40; s = 16; lvl = 1; }
  else { int q = a - 8000; x = q % 20; y = q / 20; s = 32; lvl = 2; }
  return (uint32_t)(x*s + s/2) | ((uint32_t)(y*s + s/2) << 10) | ((uint32_t)lvl << 20);
}

// ---- kA: gt structs + per-anchor staging + fg (identity layout) -----------
// v15 == r12 verbatim (best-known 190.2, absmax 0).
__global__ __launch_bounds__(TPB) void kA(P p){
  __shared__ float4 s_gtb[GG], s_gtc[GG];
  __shared__ float s_o[TPB*6];
  __shared__ int s_ng;
  int t = threadIdx.x;
  int c = blockIdx.x, b = blockIdx.y;
  int isf = dtypeFlag(p.ss);
  if (t == 0) s_ng = 0;
  {
    int s = c*TPB + t;
    if (s < SCAP) p.sel_a[b*SCAP + s] = -1;        // empty slot marker
  }
  int nel = min(TPB*6, AA*6 - c*(TPB*6));      // floats in this chunk
  if (isf){
    const float4* src = (const float4*)((const float*)p.outs + (size_t)b*AA*6 + (size_t)c*(TPB*6));
    float4* dst = (float4*)s_o;
    for (int i = t; i < nel/4; i += TPB) dst[i] = src[i];
  } else {
    const uint4* src = (const uint4*)((const bf16*)p.outs + (size_t)b*AA*6 + (size_t)c*(TPB*6));
    for (int i = t; i < nel/8; i += TPB){
      uint4 u = src[i];
      int o = i*8;
      s_o[o+0]=__uint_as_float(u.x<<16); s_o[o+1]=__uint_as_float(u.x&0xffff0000u);
      s_o[o+2]=__uint_as_float(u.y<<16); s_o[o+3]=__uint_as_float(u.y&0xffff0000u);
      s_o[o+4]=__uint_as_float(u.z<<16); s_o[o+5]=__uint_as_float(u.z&0xffff0000u);
      s_o[o+6]=__uint_as_float(u.w<<16); s_o[o+7]=__uint_as_float(u.w&0xffff0000u);
    }
  }
  __syncthreads();
  if (t < GG){
    int i = b*GG + t;
    float l0 = ld(p.labs, i*5  , isf);
    float gcx= ld(p.labs, i*5+1, isf);
    float gcy= ld(p.labs, i*5+2, isf);
    float gw = ld(p.labs, i*5+3, isf);
    float gh = ld(p.labs, i*5+4, isf);
    int valid = (l0+gcx+gcy+gw+gh) > 0.f;
    float4 vb = make_float4(gcx-gw*0.5f, gcy-gh*0.5f, gcx+gw*0.5f, gcy+gh*0.5f);
    float4 vc = make_float4(gcx, gcy, gw*gh, valid ? 1.f : 0.f);
    s_gtb[t] = vb; s_gtc[t] = vc;
    if (c == 0){ p.gtb[i] = vb; p.gtc[i] = vc; }
    if (valid) atomicMax(&s_ng, t+1);
  }
  __syncthreads();
  int ng = s_ng;
  if (c == 0 && t == 0) p.gmax[b] = ng;
  int a = c*TPB + t;
  if (a < AA){
    float cx=s_o[t*6], cy=s_o[t*6+1], w=s_o[t*6+2], h=s_o[t*6+3], ob=s_o[t*6+4], cl=s_o[t*6+5];
    int idx = b*AA + a;
    p.box4[idx] = make_float4(cx-w*0.5f, cy-h*0.5f, cx+w*0.5f, cy+h*0.5f);
    float so = 1.f/(1.f+expf(-ob));
    float sc = 1.f/(1.f+expf(-cl));
    float pccv = -logf(sqrtf(sc*so) + 1e-9f);
    float xc, yc, r; ageom(a, xc, yc, r);
    int fg = 0;
    for (int g = 0; g < ng; ++g){
      float4 gb = s_gtb[g], gc = s_gtc[g];
      bool inb = (xc>gb.x)&&(xc<gb.z)&&(yc>gb.y)&&(yc<gb.w);
      bool inc = (fabsf(xc-gc.x)<r)&&(fabsf(yc-gc.y)<r);
      fg |= (gc.w != 0.f) && (inb||inc);
    }
    float area = w*h;                       // >= 16 (w,h >= 4): sign trick safe
    p.aux2[idx] = make_float2(fg ? area : -area, __uint_as_float(apack2(a)));
    p.pcc[idx] = pccv;
    p.zl [idx] = cl;
    p.cnt[idx] = 0;
    p.own[idx] = 0x7fffffff;
  }
}

// ---- kB: per-(b,g) dyn_k + selection (identity layout, packed geom) -------
// v15 == r12 verbatim. (r13 persistent-queue REVERTED: occupancy 40->70% but
// dur 57->82 -- the loop-top barrier held 7 waves hostage during wave-0
// selection; r12's early-exit releases them. Occupancy% = residency, not
// progress.)
__global__ __launch_bounds__(TKB) void kB(P p){
  __shared__ float s_pos[PCAP];
  __shared__ float s_gcost[GCAP];
  __shared__ int   s_gpos[GCAP];
  __shared__ int   s_pcnt, s_gcnt;
  int t = threadIdx.x;
  int lane = t & 63, wid = t >> 6;
  int item = blockIdx.x;
  int b = item / GG, g = item - b*GG;       // balanced across XCDs
  if (t == 0){ s_pcnt = 0; s_gcnt = 0; }
  float4 gc = p.gtc[b*GG+g];
  if (gc.w == 0.f) return;                  // uniform exit, pre-barrier
  float4 gb = p.gtb[b*GG+g];
  float glx=gb.x, gly=gb.y, ghx=gb.z, ghy=gb.w, gcx=gc.x, gcy=gc.y, ga=gc.z;
  int base = b*AA;
  unsigned long long lmlt = (1ull<<lane) - 1ull;
  __syncthreads();                          // s_pcnt/s_gcnt init visible

  // main screen over all AA anchors; heavy math only on hits
  for (int it = 0; it < NITB; ++it){
    int pos = it*TKB + t;
    bool ovl = false, geo = false;
    float v = 0.f, cst = 0.f;
    if (pos < AA){
      float2 aux = p.aux2[base+pos];
      float4 bx  = p.box4[base+pos];
      bool fg = aux.x > 0.f;
      uint32_t u = __float_as_uint(aux.y);
      float xc = (float)(u & 1023u), yc = (float)((u>>10)&1023u);
      float r  = (float)(20u << (u>>20));
      bool inb = (xc>glx)&&(xc<ghx)&&(yc>gly)&&(yc<ghy);
      geo = inb && (fabsf(xc-gcx)<r) && (fabsf(yc-gcy)<r);   // geo => fg
      float tlx=fmaxf(glx,bx.x), tly=fmaxf(gly,bx.y);
      float brx=fminf(ghx,bx.z), bry=fminf(ghy,bx.w);
      float iw=brx-tlx, ih=bry-tly;
      ovl = fg && (iw>0.f) && (ih>0.f);
      if (ovl | geo){
        float area = fabsf(aux.x);
        float inter = fmaxf(iw,0.f)*fmaxf(ih,0.f);
        v = inter/(ga + area - inter + 1e-12f);
        if (geo) cst = p.pcc[base+pos] + 3.f*(-logf(v+1e-8f));
      }
    }
    unsigned long long m1 = __ballot(ovl);
    if (m1){
      int ldr = (int)(__ffsll(m1)-1);
      int off;
      if (lane == ldr) off = atomicAdd(&s_pcnt, __popcll(m1));
      off = __shfl(off, ldr);
      if (ovl) s_pos[off + __popcll(m1 & lmlt)] = v;
    }
    unsigned long long m2 = __ballot(geo);
    if (m2){
      int ldr = (int)(__ffsll(m2)-1);
      int off;
      if (lane == ldr) off = atomicAdd(&s_gcnt, __popcll(m2));
      off = __shfl(off, ldr);
      if (geo){
        int q = off + __popcll(m2 & lmlt);
        s_gcost[q] = cst; s_gpos[q] = pos;
      }
    }
  }
  __syncthreads();
  if (wid) return;                          // 7 waves released; wave 0 selects

  int pcnt = s_pcnt, gcnt = s_gcnt;         // gcnt <= 75 < GCAP

  // dk: top-10 positives by pop-extraction over s_pos (values only;
  // descending add order == jnp top_k sum order; zeros add exactly 0)
  float lmax = -1.f;
  for (int i = lane; i < pcnt; i += 64) lmax = fmaxf(lmax, s_pos[i]);
  float sum = 0.f;
  for (int k = 0; k < 10; ++k){
    float gv = lmax;
#pragma unroll
    for (int off=32; off; off>>=1) gv = fmaxf(gv, __shfl_xor(gv, off));
    if (gv <= 0.f) break;
    sum += gv;
    unsigned long long ms = __ballot(lmax == gv);
    if ((int)(__ffsll(ms)-1) == lane){      // unique owner: remove 1 instance
      bool fnd = false; float nl = -1.f;
      for (int i = lane; i < pcnt; i += 64){
        float vv = s_pos[i];
        if (!fnd && vv == gv){ fnd = true; vv = -1.f; s_pos[i] = vv; }
        nl = fmaxf(nl, vv);
      }
      lmax = nl;
    }
  }
  int dk = (int)sum; if (dk<1) dk=1; if (dk>10) dk=10;

  // selection among geo (<=2 entries/lane; all geo < all non-geo cost)
  float c0=3.0e38f, c1=3.0e38f; int p0=0x7fffffff, p1=0x7fffffff;
  if (lane < gcnt){ c0 = s_gcost[lane]; p0 = s_gpos[lane]; }
  if (lane+64 < gcnt){ c1 = s_gcost[lane+64]; p1 = s_gpos[lane+64]; }
  if (c1 < c0 || (c1==c0 && p1<p0)){
    float tc=c0; c0=c1; c1=tc; int tp=p0; p0=p1; p1=tp;
  }
  int mysel = -1, take = 0;
  for (int k = 0; k < dk; ++k){
    float gv=c0; int gi=p0;
#pragma unroll
    for (int off=32; off; off>>=1){
      float ov=__shfl_xor(gv,off); int oi=__shfl_xor(gi,off);
      if (ov<gv || (ov==gv && oi<gi)){ gv=ov; gi=oi; }
    }
    if (gv >= 2.9e38f) break;               // geo exhausted
    if (lane == k) mysel = gi;
    take++;
    if (c0==gv && p0==gi){ c0=c1; p0=p1; c1=3.0e38f; p1=0x7fffffff; }
  }

  // rare fallback: need (dk-take) non-geo picks; exact k-th smallest via
  // repeated rescan excluding previous picks by strict lex >
  float lastc = -3.0e38f; int lastp = -1;
  for (int k = take; k < dk; ++k){
    float bc = 3.0e38f; int bp = 0x7fffffff;
    int n64 = (AA + 63) >> 6;
    for (int it = 0; it < n64; ++it){
      int pos = (it<<6) + lane;
      if (pos < AA){
        float2 aux = p.aux2[base+pos];
        bool fg = aux.x > 0.f;
        if (fg){
          uint32_t u = __float_as_uint(aux.y);
          float xc = (float)(u & 1023u), yc = (float)((u>>10)&1023u);
          float r  = (float)(20u << (u>>20));
          bool inb = (xc>glx)&&(xc<ghx)&&(yc>gly)&&(yc<ghy);
          bool geo2 = inb && (fabsf(xc-gcx)<r) && (fabsf(yc-gcy)<r);
          if (!geo2){
            float4 bx = p.box4[base+pos];
            float tlx=fmaxf(glx,bx.x), tly=fmaxf(gly,bx.y);
            float brx=fminf(ghx,bx.z), bry=fminf(ghy,bx.w);
            float iw=fmaxf(brx-tlx,0.f), ih=fmaxf(bry-tly,0.f);
            float inter=iw*ih;
            float area = fabsf(aux.x);
            float v = inter/(ga + area - inter + 1e-12f);
            float cst = p.pcc[base+pos] + 3.f*(-logf(v+1e-8f)) + 100000.f;
            bool gt = (cst > lastc) || (cst == lastc && pos > lastp);
            bool lt = (cst < bc)   || (cst == bc   && pos < bp);
            if (gt && lt){ bc = cst; bp = pos; }
          }
        }
      }
    }
#pragma unroll
    for (int off=32; off; off>>=1){
      float ov=__shfl_xor(bc,off); int oi=__shfl_xor(bp,off);
      if (ov<bc || (ov==bc && oi<bp)){ bc=ov; bp=oi; }
    }
    if (bc >= 2.9e38f) break;               // candidates exhausted
    if (lane == k) mysel = bp;
    lastc = bc; lastp = bp;
  }

  if (mysel >= 0){                          // lanes 0..dk-1 hold selections
    int a = mysel;                          // pos == anchor id
    float4 bx = p.box4[base+a];
    float area = fabsf(p.aux2[base+a].x);
    float tlx=fmaxf(glx,bx.x), tly=fmaxf(gly,bx.y);
    float brx=fminf(ghx,bx.z), bry=fminf(ghy,bx.w);
    float iw=fmaxf(brx-tlx,0.f), ih=fmaxf(bry-tly,0.f);
    float inter=iw*ih;
    float iou=inter/(ga + area - inter + 1e-12f);
    int slot = g*10 + lane;                 // deterministic slot id
    p.sel_a [b*SCAP + slot] = a;
    p.sel_iou[b*SCAP + slot] = iou;
    atomicAdd(&p.cnt[base+a], 1);
    atomicMin(&p.own[base+a], slot);        // commutative -> deterministic owner
  }
}

// ---- kR: per-(b,g) resolution + BCE partials (grid 3200, 1 wave) ----------
// v15: conflicted-anchor recompute WAVE-PARALLELIZED. r12's version ran the
// ng-loop serially on ONE lane (2 dependent L2 loads x ~100 iters ~= 16us
// latency chain while 63 lanes idle -- same serial-chain shape as r7's 375us
// kernel). Now: ballot conflicted slots; for each, 64 lanes split the g2
// loop (<=2 iters/lane) and lex-min reduce on (cost,g2) == serial first-
// index argmin (strict < keeps earliest min). iou delivered to owner lane;
// per-lane BCE + butterfly sum byte-identical to r12 -> bit-exact.
__global__ __launch_bounds__(64) void kR(P p){
  int lane = threadIdx.x;
  int item = blockIdx.x;
  int b = item / GG, g = item - b*GG;
  int base = b*AA;
  int a = -1, cgt = 0;
  bool ownr = false;
  float iouv = 0.f;
  if (lane < 10){
    int slot = g*10 + lane;
    a = p.sel_a[b*SCAP + slot];
    if (a >= 0 && p.own[base+a] == slot){
      ownr = true;
      cgt = p.cnt[base+a];
      iouv = p.sel_iou[b*SCAP + slot];      // final value when cgt==1
    }
  }
  unsigned long long cm = __ballot(ownr && cgt > 1);
  if (cm){
    int ng = p.gmax[b];
    while (cm){
      int s = (int)(__ffsll(cm)-1); cm &= cm - 1ull;
      int aa = __shfl(a, s);
      float area = fabsf(p.aux2[base+aa].x);
      float pccv = p.pcc[base+aa];
      float4 bx = p.box4[base+aa];
      float xc,yc,r; ageom(aa,xc,yc,r);
      float bc = 3.9e38f, bi = 0.f; int bg = 0x7fffffff;
      for (int g2 = lane; g2 < ng; g2 += 64){
        float4 gbb = p.gtb[b*GG+g2], gcc = p.gtc[b*GG+g2];
        float cost, iou2 = 0.f;
        if (gcc.w != 0.f){
          float tlx=fmaxf(gbb.x,bx.x), tly=fmaxf(gbb.y,bx.y);
          float brx=fminf(gbb.z,bx.z), bry=fminf(gbb.w,bx.w);
          float iw=fmaxf(brx-tlx,0.f), ih=fmaxf(bry-tly,0.f);
          float inter=iw*ih;
          iou2 = inter/(gcc.z + area - inter + 1e-12f);
          bool inb=(xc>gbb.x)&&(xc<gbb.z)&&(yc>gbb.y)&&(yc<gbb.w);
          bool inc=(fabsf(xc-gcc.x)<r)&&(fabsf(yc-gcc.y)<r);
          cost = pccv + 3.f*(-logf(iou2+1e-8f)) + ((inb&&inc)?0.f:100000.f);
        } else cost = 1e9f;
        if (cost < bc){ bc=cost; bi=iou2; bg=g2; }   // lane-local first-min
      }
#pragma unroll
      for (int off=32; off; off>>=1){
        float oc=__shfl_xor(bc,off), oi=__shfl_xor(bi,off);
        int og=__shfl_xor(bg,off);
        if (oc<bc || (oc==bc && og<bg)){ bc=oc; bi=oi; bg=og; }
      }
      if (lane == s) iouv = bi;             // deliver to owning lane
    }
  }
  float bce = 0.f, fgv = 0.f;
  if (lane < 10 && ownr){
    float z = p.zl[base+a];
    float e = expf(-fabsf(z));
    float spz = fmaxf(z,0.f)+log1pf(e);
    float spn = fmaxf(-z,0.f)+log1pf(e);
    bce = iouv*spn + (1.f-iouv)*spz;
    fgv = 1.f;
  }
#pragma unroll
  for (int off=32; off; off>>=1){
    bce += __shfl_xor(bce, off);
    fgv += __shfl_xor(fgv, off);
  }
  if (lane == 0){ p.pb[item] = bce; p.pf[item] = fgv; }
}

// ---- kD: reduce 3200 partials + finalize (1 block) -------------------------
__global__ __launch_bounds__(TPB) void kD(P p){
  int t = threadIdx.x;
  float sb=0.f, sf=0.f;
  for (int i = t; i < NB2; i += TPB){ sb += p.pb[i]; sf += p.pf[i]; }
#pragma unroll
  for (int off=32; off; off>>=1){
    sb += __shfl_xor(sb, off);
    sf += __shfl_xor(sf, off);
  }
  __shared__ float s_b[4], s_f[4];
  int lane = t & 63, wid = t >> 6;
  if (lane==0){ s_b[wid]=sb; s_f[wid]=sf; }
  __syncthreads();
  if (t==0){
    float tb=s_b[0]+s_b[1]+s_b[2]+s_b[3];
    float tf=s_f[0]+s_f[1]+s_f[2]+s_f[3];
    p.out[0] = tb / fmaxf(tf, 1.f);
  }
}

extern "C" void kernel_launch(void* const* d_in, const int* in_sizes, int n_in,
                              void* d_out, int out_size, void* d_ws, size_t ws_size,
                              hipStream_t stream) {
  P p;
  p.outs = d_in[0];
  p.labs = d_in[1];
  p.ss   = d_in[4];
  char* w = (char*)d_ws;
  p.box4  = (float4*)w; w += (size_t)BA*sizeof(float4);
  p.gtb   = (float4*)w; w += (size_t)NG*sizeof(float4);
  p.gtc   = (float4*)w; w += (size_t)NG*sizeof(float4);
  p.aux2  = (float2*)w; w += (size_t)BA*sizeof(float2);
  p.pcc   = (float*)w;  w += (size_t)BA*sizeof(float);
  p.zl    = (float*)w;  w += (size_t)BA*sizeof(float);
  p.sel_a = (int*)w;    w += (size_t)BB*SCAP*sizeof(int);
  p.sel_iou=(float*)w;  w += (size_t)BB*SCAP*sizeof(float);
  p.cnt   = (int*)w;    w += (size_t)BA*sizeof(int);
  p.own   = (int*)w;    w += (size_t)BA*sizeof(int);
  p.gmax  = (int*)w;    w += (size_t)BB*sizeof(int);
  p.pb    = (float*)w;  w += (size_t)NB2*sizeof(float);
  p.pf    = (float*)w;  w += (size_t)NB2*sizeof(float);
  p.out   = (float*)d_out;

  kA<<<dim3(NCH, BB), TPB, 0, stream>>>(p);
  kB<<<BB*GG, TKB, 0, stream>>>(p);
  kR<<<NB2, 64, 0, stream>>>(p);
  kD<<<1, TPB, 0, stream>>>(p);
}